// Round 10
// baseline (572.263 us; speedup 1.0000x reference)
//
#include <hip/hip_runtime.h>
#include <math.h>

// ---------------------------------------------------------------------------
// InfoNCE on MI355X — v13.
// T1[i,j] = tail(relu(hx[j]+hy[i]+b1)) = fused GEMM M=262144, N=512, K=512,
// A formed on the fly; 2 MFMA products (A bf16, B hi/lo split), 32x32x16.
// v13 = bank the validated pieces, avoid v12's poison:
//  - v12 post-mortem: per-block ACQUIRE __threadfence scattered through the
//    kernel invalidates the XCD L2 repeatedly (FETCH 8.8->76 MB, util 22%).
//    Release fences (wbl2) + ONE final acquire are cheap.
//  - pair = v8's exact body (fastest measured, 298 us) + v10's validated
//    atomic epilogue (diag->t0g, row exp-sums->atomicAdd; T1/rowlse gone)
//    + v12's validated last-block reduction (release fence + rank per
//    block; single acquire in the one last block). No spin.
//  - prep reworked: 8 rows/block, k-outer register blocking -> W1 streamed
//    once per block (32 MB total L2 traffic vs 256 MB); rsm/ctl zeroing
//    folded in; memset dispatch removed. 2 dispatches total (was 4).
// ---------------------------------------------------------------------------

typedef __bf16 bf16x8 __attribute__((ext_vector_type(8)));
typedef float  f32x16 __attribute__((ext_vector_type(16)));

#define H     512
#define NPTS  512
#define XD    128
#define SPA   520   // A-tile LDS row stride (elems): 1040 B (0 conflicts)
#define PLS   12    // epilogue partial-scratch row stride (f32)
#define NTILE 4096  // 64 i-groups x 64 j-groups (M-tile 64 = 8i x 8j)

// ---------------- prep: hx, hy(+b1); W2 repack; zero rsm/ctl --------------
// grid 640 x 256 thr. b<128: 8 rows of hx/hy per block (k-outer, W1 read
// once per block). b>=128: W2 column n=b-128 -> fragment-major bf16 hi/lo.
__global__ __launch_bounds__(256) void prep_kernel(
    const float* __restrict__ x, const float* __restrict__ y,
    const float* __restrict__ W1x, const float* __restrict__ W1y,
    const float* __restrict__ b1, const float* __restrict__ W2,
    float* __restrict__ hx, float* __restrict__ hy,
    __bf16* __restrict__ w2h, __bf16* __restrict__ w2l,
    float* __restrict__ rsm, int* __restrict__ ctl) {
  __shared__ float xs[8 * XD];
  const int b = blockIdx.x;
  const int t = threadIdx.x;
  if (b < 128) {
    const bool isY = (b >= 64);
    const int r0 = (isY ? b - 64 : b) * 8;
    const float* src = isY ? y : x;      // [NPTS][XD]
    const float* W   = isY ? W1y : W1x;  // [XD][H]
    float* dst = isY ? hy : hx;
    for (int i = t; i < 8 * XD; i += 256) xs[i] = src[r0 * XD + i];
    __syncthreads();
    float a0[8], a1[8];
#pragma unroll
    for (int r = 0; r < 8; ++r) { a0[r] = 0.f; a1[r] = 0.f; }
    for (int k = 0; k < XD; ++k) {       // W1 row k read once, used 8x
      const float w0 = W[k * H + t];
      const float w1 = W[k * H + t + 256];
#pragma unroll
      for (int r = 0; r < 8; ++r) {
        const float xv = xs[r * XD + k];   // LDS broadcast
        a0[r] = fmaf(xv, w0, a0[r]);
        a1[r] = fmaf(xv, w1, a1[r]);
      }
    }
    const float c0 = isY ? b1[t] : 0.f;        // fold b1 into hy
    const float c1 = isY ? b1[t + 256] : 0.f;
#pragma unroll
    for (int r = 0; r < 8; ++r) {
      dst[(r0 + r) * H + t]       = a0[r] + c0;
      dst[(r0 + r) * H + t + 256] = a1[r] + c1;
    }
  } else {
    // W2[k][n] -> 32x32x16-fragment-major:
    // idx = ((n>>5)*32 + (k>>4))*512 + (n&31)*16 + (k&15)
    const int n = b - 128;
    if (n == 0) { rsm[t] = 0.f; rsm[t + 256] = 0.f; if (t == 0) ctl[0] = 0; }
    for (int k = t; k < H; k += 256) {
      float v = W2[k * H + n];
      __bf16 hi = (__bf16)v;
      float lo = v - (float)hi;
      const int idx = (((n >> 5) * 32) + (k >> 4)) * 512 + (n & 31) * 16 + (k & 15);
      w2h[idx] = hi;
      w2l[idx] = (__bf16)lo;
    }
  }
}

// ---------------- pair GEMM + fused tail + row sums + final ---------------
// grid 4096 = 64 i-groups x 64 j-groups; M-tile = 64 pairs (8 i x 8 j).
// 512 threads = 8 waves; wave w = n-group: cols [w*64, w*64+64)
// (2 m-tiles x 2 n-tiles; acc[2][2] f32x16). K in 32 half-steps of 16;
// A/B register-double-buffered; barrier-free K-loop; 66.5 KB LDS ->
// 2 blocks/CU. Epilogue: softplus -> diag to t0g, row exp-sums atomicAdd.
// Last block (rank NTILE-1 via ctl) reduces t0g/log(rsm) -> out.
__global__ __launch_bounds__(512, 4) void pair_kernel(
    const float* __restrict__ hx, const float* __restrict__ hy,
    const __bf16* __restrict__ w2h, const __bf16* __restrict__ w2l,
    const float* __restrict__ b2, const float* __restrict__ W3,
    const float* __restrict__ b3, float* __restrict__ t0g,
    float* __restrict__ rsm, int* __restrict__ ctl,
    float* __restrict__ out) {
  extern __shared__ __align__(16) __bf16 Ah[];   // [64][SPA] = 66560 B
  __shared__ float s1[8], s2[8];
  __shared__ int rank_s;

  const int t    = threadIdx.x;
  const int i0   = (blockIdx.x >> 6) * 8;
  const int j0   = (blockIdx.x & 63) * 8;
  const int wave = t >> 6;        // n-group 0..7 (cols wave*64..wave*64+63)
  const int lane = t & 63;
  const int r31  = lane & 31;
  const int half = lane >> 5;

  const int boff = r31 * 16 + half * 8;
  const __bf16* w2hW = w2h + wave * 32768 + boff;
  const __bf16* w2lW = w2l + wave * 32768 + boff;

  // issue B loads for half-step 0 before staging (land during it)
  bf16x8 Bh[2][2], Bl[2][2];
  Bh[0][0] = *(const bf16x8*)(w2hW);
  Bh[0][1] = *(const bf16x8*)(w2hW + 16384);
  Bl[0][0] = *(const bf16x8*)(w2lW);
  Bl[0][1] = *(const bf16x8*)(w2lW + 16384);

  // ---- upfront staging of the whole 64 x 512 A tile ------------------
  {
    const int sm = t >> 3;        // pair row 0..63  (ti = sm>>3, tj = sm&7)
    const int sl = t & 7;
    const float* hxp = hx + (j0 + (sm & 7)) * H;
    const float* hyp = hy + (i0 + (sm >> 3)) * H;
    __bf16* arow = Ah + sm * SPA;
#pragma unroll
    for (int c = 0; c < 8; ++c) {
      const int k = sl * 8 + c * 64;
      float4 x0 = *(const float4*)(hxp + k);
      float4 x1 = *(const float4*)(hxp + k + 4);
      float4 y0 = *(const float4*)(hyp + k);
      float4 y1 = *(const float4*)(hyp + k + 4);
      float a[8] = {x0.x + y0.x, x0.y + y0.y, x0.z + y0.z, x0.w + y0.w,
                    x1.x + y1.x, x1.y + y1.y, x1.z + y1.z, x1.w + y1.w};
      bf16x8 hv;
#pragma unroll
      for (int e = 0; e < 8; ++e) {
        float v = a[e] > 0.f ? a[e] : 0.f;   // first relu
        hv[e] = (__bf16)v;
      }
      *(bf16x8*)(&arow[k]) = hv;
    }
  }

  f32x16 acc[2][2] = {};
  __syncthreads();   // staging complete; only barrier before epilogue

  const __bf16* pA = Ah + r31 * SPA + half * 8;
  bf16x8 Ab[2][2];
  Ab[0][0] = *(const bf16x8*)(pA);
  Ab[0][1] = *(const bf16x8*)(pA + 32 * SPA);

  // ---- barrier-free K-loop: 32 half-steps of K=16 (v8 body) ----------
#pragma unroll
  for (int hs = 0; hs < 32; ++hs) {
    const int cur = hs & 1;
    if (hs < 31) {   // prefetch B and A for next half-step
      const int bo = (hs + 1) * 512;
      Bh[cur ^ 1][0] = *(const bf16x8*)(w2hW + bo);
      Bh[cur ^ 1][1] = *(const bf16x8*)(w2hW + 16384 + bo);
      Bl[cur ^ 1][0] = *(const bf16x8*)(w2lW + bo);
      Bl[cur ^ 1][1] = *(const bf16x8*)(w2lW + 16384 + bo);
      Ab[cur ^ 1][0] = *(const bf16x8*)(pA + (hs + 1) * 16);
      Ab[cur ^ 1][1] = *(const bf16x8*)(pA + 32 * SPA + (hs + 1) * 16);
    }
    __builtin_amdgcn_s_setprio(1);
    acc[0][0] = __builtin_amdgcn_mfma_f32_32x32x16_bf16(Ab[cur][0], Bh[cur][0], acc[0][0], 0, 0, 0);
    acc[0][1] = __builtin_amdgcn_mfma_f32_32x32x16_bf16(Ab[cur][0], Bh[cur][1], acc[0][1], 0, 0, 0);
    acc[1][0] = __builtin_amdgcn_mfma_f32_32x32x16_bf16(Ab[cur][1], Bh[cur][0], acc[1][0], 0, 0, 0);
    acc[1][1] = __builtin_amdgcn_mfma_f32_32x32x16_bf16(Ab[cur][1], Bh[cur][1], acc[1][1], 0, 0, 0);
    acc[0][0] = __builtin_amdgcn_mfma_f32_32x32x16_bf16(Ab[cur][0], Bl[cur][0], acc[0][0], 0, 0, 0);
    acc[0][1] = __builtin_amdgcn_mfma_f32_32x32x16_bf16(Ab[cur][0], Bl[cur][1], acc[0][1], 0, 0, 0);
    acc[1][0] = __builtin_amdgcn_mfma_f32_32x32x16_bf16(Ab[cur][1], Bl[cur][0], acc[1][0], 0, 0, 0);
    acc[1][1] = __builtin_amdgcn_mfma_f32_32x32x16_bf16(Ab[cur][1], Bl[cur][1], acc[1][1], 0, 0, 0);
    __builtin_amdgcn_s_setprio(0);
  }

  __syncthreads();   // all waves done reading Ah -> safe to alias its LDS

  // ---- epilogue: relu(h2+b2)*W3, shfl-reduce, softplus, row sums -----
  float* PL = (float*)Ah;            // [64][PLS], aliases dead A tile
  const float bb0 = b2[wave * 64 + r31];
  const float bb1 = b2[wave * 64 + 32 + r31];
  const float w30 = W3[wave * 64 + r31];
  const float w31 = W3[wave * 64 + 32 + r31];
#pragma unroll
  for (int mt = 0; mt < 2; ++mt) {
#pragma unroll
    for (int r = 0; r < 16; ++r) {
      float v0 = acc[mt][0][r] + bb0;
      float v1 = acc[mt][1][r] + bb1;
      v0 = v0 > 0.f ? v0 : 0.f;            // second relu
      v1 = v1 > 0.f ? v1 : 0.f;
      float p = fmaf(v0, w30, v1 * w31);
      p += __shfl_xor(p, 1);
      p += __shfl_xor(p, 2);
      p += __shfl_xor(p, 4);
      p += __shfl_xor(p, 8);
      p += __shfl_xor(p, 16);
      if (r31 == 0) {
        const int row = mt * 32 + (r & 3) + 8 * (r >> 2) + 4 * half;
        PL[row * PLS + wave] = p;
      }
    }
  }
  __syncthreads();
  if (t < 64) {
    float4 q0 = *(const float4*)(PL + t * PLS);
    float4 q1 = *(const float4*)(PL + t * PLS + 4);
    float s = b3[0] + q0.x + q0.y + q0.z + q0.w + q1.x + q1.y + q1.z + q1.w;
    const float sp = s > 0.f ? s + log1pf(expf(-s)) : log1pf(expf(s));
    const int ti = t >> 3, tj = t & 7;
    const int gi = i0 + ti, gj = j0 + tj;
    if (gi == gj) t0g[gi] = sp;            // diag == T0, written exactly once
    float e = expf(sp);
    e += __shfl_xor(e, 1);                 // sum over this tile's 8 j's
    e += __shfl_xor(e, 2);
    e += __shfl_xor(e, 4);
    if (tj == 0) atomicAdd(rsm + gi, e);
  }
  __syncthreads();   // all stores/atomics of this block drained (vmcnt 0)

  // ---- last block does the final reduction (single acquire fence) ----
  if (t == 0) {
    __threadfence();                       // release: wbl2 (dirty set tiny)
    rank_s = atomicAdd(ctl, 1);
  }
  __syncthreads();
  if (rank_s == NTILE - 1) {
    __threadfence();                       // acquire: executed ONCE on chip
    float a = t0g[t];
    float l = logf(rsm[t]);
#pragma unroll
    for (int off = 1; off < 64; off <<= 1) {
      a += __shfl_xor(a, off);
      l += __shfl_xor(l, off);
    }
    if (lane == 0) { s1[wave] = a; s2[wave] = l; }
    __syncthreads();
    if (t == 0) {
      float sa = 0.f, sb = 0.f;
#pragma unroll
      for (int i = 0; i < 8; ++i) { sa += s1[i]; sb += s2[i]; }
      out[0] = sa / 512.0f - sb / 512.0f + logf(512.0f);
    }
  }
}

// ---------------------------------------------------------------------------
extern "C" void kernel_launch(void* const* d_in, const int* in_sizes, int n_in,
                              void* d_out, int out_size, void* d_ws, size_t ws_size,
                              hipStream_t stream) {
  const float* x   = (const float*)d_in[0];
  const float* y   = (const float*)d_in[1];
  const float* W1x = (const float*)d_in[2];
  const float* W1y = (const float*)d_in[3];
  const float* b1  = (const float*)d_in[4];
  const float* W2  = (const float*)d_in[5];
  const float* b2  = (const float*)d_in[6];
  const float* W3  = (const float*)d_in[7];
  const float* b3  = (const float*)d_in[8];

  float* ws = (float*)d_ws;
  float* hx  = ws;                        // 512*512 f32
  float* hy  = ws + 262144;               // 512*512 f32
  float* t0g = ws + 524288;               // 512 f32 (diag = T0)
  float* rsm = ws + 524288 + 512;         // 512 f32 (row exp-sums)
  int*   ctl = (int*)(ws + 524288 + 1024);// rank counter
  __bf16* w2h = (__bf16*)(ws + 786432);   // 512*512 bf16 (fragment-major)
  __bf16* w2l = w2h + 262144;             // 512*512 bf16
  float* out = (float*)d_out;

  static bool configured = false;
  if (!configured) {
    hipFuncSetAttribute(reinterpret_cast<const void*>(pair_kernel),
                        hipFuncAttributeMaxDynamicSharedMemorySize,
                        64 * SPA * 2);
    configured = true;
  }

  hipLaunchKernelGGL(prep_kernel, dim3(640), dim3(256), 0, stream,
                     x, y, W1x, W1y, b1, W2, hx, hy, w2h, w2l, rsm, ctl);
  hipLaunchKernelGGL(pair_kernel, dim3(NTILE), dim3(512), 64 * SPA * 2, stream,
                     hx, hy, w2h, w2l, b2, W3, b3, t0g, rsm, ctl, out);
}

// Round 11
// 467.955 us; speedup vs baseline: 1.2229x; 1.2229x over previous
//
#include <hip/hip_runtime.h>
#include <math.h>

// ---------------------------------------------------------------------------
// InfoNCE on MI355X — v14.
// T1[i,j] = tail(relu(hx[j]+hy[i]+b1)) = fused GEMM M=262144, N=512, K=512,
// A formed on the fly; 2 MFMA products (A bf16, B hi/lo split), 32x32x16.
// v14 vs v13: FENCE-FREE single-boundary pipeline. v13's poison was
// per-block __threadfence (buffer_wbl2) x 4096 blocks force-flushing the
// ~131 MB of dirty spill scratch in L2 -> 540 MB HBM writes / 249 MB
// refetches. v14 deletes ALL fences. Ordering argument: __syncthreads
// emits s_waitcnt vmcnt(0) first, so each block's rsm atomicAdds + t0g
// coherent stores are COMPLETE at the coherence point before the block's
// rank atomicAdd(ctl) issues; the block drawing rank NTILE-1 therefore
// sees all contributions, and reads t0g/rsm with __hip_atomic_load
// (agent scope, per-access coherent - no cache flush). Atomic epilogue
// itself proven free in v10 (WRITE 130 KB). Pair body = v8's fastest
// (298 us, full-unroll; 131 MB scratch spill accepted - benign unfenced).
// prep = v13's (validated, ~8 us, zeroes rsm/ctl each run).
// ---------------------------------------------------------------------------

typedef __bf16 bf16x8 __attribute__((ext_vector_type(8)));
typedef float  f32x16 __attribute__((ext_vector_type(16)));

#define H     512
#define NPTS  512
#define XD    128
#define SPA   520   // A-tile LDS row stride (elems): 1040 B (0 conflicts)
#define PLS   12    // epilogue partial-scratch row stride (f32)
#define NTILE 4096  // 64 i-groups x 64 j-groups (M-tile 64 = 8i x 8j)

// ---------------- prep: hx, hy(+b1); W2 repack; zero rsm/ctl --------------
__global__ __launch_bounds__(256) void prep_kernel(
    const float* __restrict__ x, const float* __restrict__ y,
    const float* __restrict__ W1x, const float* __restrict__ W1y,
    const float* __restrict__ b1, const float* __restrict__ W2,
    float* __restrict__ hx, float* __restrict__ hy,
    __bf16* __restrict__ w2h, __bf16* __restrict__ w2l,
    float* __restrict__ rsm, int* __restrict__ ctl) {
  __shared__ float xs[8 * XD];
  const int b = blockIdx.x;
  const int t = threadIdx.x;
  if (b < 128) {
    const bool isY = (b >= 64);
    const int r0 = (isY ? b - 64 : b) * 8;
    const float* src = isY ? y : x;      // [NPTS][XD]
    const float* W   = isY ? W1y : W1x;  // [XD][H]
    float* dst = isY ? hy : hx;
    for (int i = t; i < 8 * XD; i += 256) xs[i] = src[r0 * XD + i];
    __syncthreads();
    float a0[8], a1[8];
#pragma unroll
    for (int r = 0; r < 8; ++r) { a0[r] = 0.f; a1[r] = 0.f; }
    for (int k = 0; k < XD; ++k) {       // W1 row k read once, used 8x
      const float w0 = W[k * H + t];
      const float w1 = W[k * H + t + 256];
#pragma unroll
      for (int r = 0; r < 8; ++r) {
        const float xv = xs[r * XD + k];   // LDS broadcast
        a0[r] = fmaf(xv, w0, a0[r]);
        a1[r] = fmaf(xv, w1, a1[r]);
      }
    }
    const float c0 = isY ? b1[t] : 0.f;        // fold b1 into hy
    const float c1 = isY ? b1[t + 256] : 0.f;
#pragma unroll
    for (int r = 0; r < 8; ++r) {
      dst[(r0 + r) * H + t]       = a0[r] + c0;
      dst[(r0 + r) * H + t + 256] = a1[r] + c1;
    }
  } else {
    // W2[k][n] -> 32x32x16-fragment-major:
    // idx = ((n>>5)*32 + (k>>4))*512 + (n&31)*16 + (k&15)
    const int n = b - 128;
    if (n == 0) { rsm[t] = 0.f; rsm[t + 256] = 0.f; if (t == 0) ctl[0] = 0; }
    for (int k = t; k < H; k += 256) {
      float v = W2[k * H + n];
      __bf16 hi = (__bf16)v;
      float lo = v - (float)hi;
      const int idx = (((n >> 5) * 32) + (k >> 4)) * 512 + (n & 31) * 16 + (k & 15);
      w2h[idx] = hi;
      w2l[idx] = (__bf16)lo;
    }
  }
}

// ---------------- pair GEMM + fused tail + row sums + final ---------------
// grid 4096; M-tile 64 (8i x 8j); 512 thr / 8 waves; wave tile 64x64
// (acc[2][2] f32x16); K in 32 half-steps of 16, A/B reg-double-buffered,
// barrier-free (v8 body). Epilogue: softplus -> diag coherent-store to t0g,
// row exp-sums atomicAdd(rsm). Rank via atomicAdd(ctl) — NO FENCES; the
// vmcnt(0) drain inside __syncthreads orders data atomics before rank.
// Block with rank NTILE-1 reduces via agent-scope atomic loads.
__global__ __launch_bounds__(512, 4) void pair_kernel(
    const float* __restrict__ hx, const float* __restrict__ hy,
    const __bf16* __restrict__ w2h, const __bf16* __restrict__ w2l,
    const float* __restrict__ b2, const float* __restrict__ W3,
    const float* __restrict__ b3, float* __restrict__ t0g,
    float* __restrict__ rsm, int* __restrict__ ctl,
    float* __restrict__ out) {
  extern __shared__ __align__(16) __bf16 Ah[];   // [64][SPA] = 66560 B
  __shared__ float s1[8], s2[8];
  __shared__ int rank_s;

  const int t    = threadIdx.x;
  const int i0   = (blockIdx.x >> 6) * 8;
  const int j0   = (blockIdx.x & 63) * 8;
  const int wave = t >> 6;        // n-group 0..7 (cols wave*64..wave*64+63)
  const int lane = t & 63;
  const int r31  = lane & 31;
  const int half = lane >> 5;

  const int boff = r31 * 16 + half * 8;
  const __bf16* w2hW = w2h + wave * 32768 + boff;
  const __bf16* w2lW = w2l + wave * 32768 + boff;

  // issue B loads for half-step 0 before staging (land during it)
  bf16x8 Bh[2][2], Bl[2][2];
  Bh[0][0] = *(const bf16x8*)(w2hW);
  Bh[0][1] = *(const bf16x8*)(w2hW + 16384);
  Bl[0][0] = *(const bf16x8*)(w2lW);
  Bl[0][1] = *(const bf16x8*)(w2lW + 16384);

  // ---- upfront staging of the whole 64 x 512 A tile ------------------
  {
    const int sm = t >> 3;        // pair row 0..63  (ti = sm>>3, tj = sm&7)
    const int sl = t & 7;
    const float* hxp = hx + (j0 + (sm & 7)) * H;
    const float* hyp = hy + (i0 + (sm >> 3)) * H;
    __bf16* arow = Ah + sm * SPA;
#pragma unroll
    for (int c = 0; c < 8; ++c) {
      const int k = sl * 8 + c * 64;
      float4 x0 = *(const float4*)(hxp + k);
      float4 x1 = *(const float4*)(hxp + k + 4);
      float4 y0 = *(const float4*)(hyp + k);
      float4 y1 = *(const float4*)(hyp + k + 4);
      float a[8] = {x0.x + y0.x, x0.y + y0.y, x0.z + y0.z, x0.w + y0.w,
                    x1.x + y1.x, x1.y + y1.y, x1.z + y1.z, x1.w + y1.w};
      bf16x8 hv;
#pragma unroll
      for (int e = 0; e < 8; ++e) {
        float v = a[e] > 0.f ? a[e] : 0.f;   // first relu
        hv[e] = (__bf16)v;
      }
      *(bf16x8*)(&arow[k]) = hv;
    }
  }

  f32x16 acc[2][2] = {};
  __syncthreads();   // staging complete; only barrier before epilogue

  const __bf16* pA = Ah + r31 * SPA + half * 8;
  bf16x8 Ab[2][2];
  Ab[0][0] = *(const bf16x8*)(pA);
  Ab[0][1] = *(const bf16x8*)(pA + 32 * SPA);

  // ---- barrier-free K-loop: 32 half-steps of K=16 (v8 body) ----------
#pragma unroll
  for (int hs = 0; hs < 32; ++hs) {
    const int cur = hs & 1;
    if (hs < 31) {   // prefetch B and A for next half-step
      const int bo = (hs + 1) * 512;
      Bh[cur ^ 1][0] = *(const bf16x8*)(w2hW + bo);
      Bh[cur ^ 1][1] = *(const bf16x8*)(w2hW + 16384 + bo);
      Bl[cur ^ 1][0] = *(const bf16x8*)(w2lW + bo);
      Bl[cur ^ 1][1] = *(const bf16x8*)(w2lW + 16384 + bo);
      Ab[cur ^ 1][0] = *(const bf16x8*)(pA + (hs + 1) * 16);
      Ab[cur ^ 1][1] = *(const bf16x8*)(pA + 32 * SPA + (hs + 1) * 16);
    }
    __builtin_amdgcn_s_setprio(1);
    acc[0][0] = __builtin_amdgcn_mfma_f32_32x32x16_bf16(Ab[cur][0], Bh[cur][0], acc[0][0], 0, 0, 0);
    acc[0][1] = __builtin_amdgcn_mfma_f32_32x32x16_bf16(Ab[cur][0], Bh[cur][1], acc[0][1], 0, 0, 0);
    acc[1][0] = __builtin_amdgcn_mfma_f32_32x32x16_bf16(Ab[cur][1], Bh[cur][0], acc[1][0], 0, 0, 0);
    acc[1][1] = __builtin_amdgcn_mfma_f32_32x32x16_bf16(Ab[cur][1], Bh[cur][1], acc[1][1], 0, 0, 0);
    acc[0][0] = __builtin_amdgcn_mfma_f32_32x32x16_bf16(Ab[cur][0], Bl[cur][0], acc[0][0], 0, 0, 0);
    acc[0][1] = __builtin_amdgcn_mfma_f32_32x32x16_bf16(Ab[cur][0], Bl[cur][1], acc[0][1], 0, 0, 0);
    acc[1][0] = __builtin_amdgcn_mfma_f32_32x32x16_bf16(Ab[cur][1], Bl[cur][0], acc[1][0], 0, 0, 0);
    acc[1][1] = __builtin_amdgcn_mfma_f32_32x32x16_bf16(Ab[cur][1], Bl[cur][1], acc[1][1], 0, 0, 0);
    __builtin_amdgcn_s_setprio(0);
  }

  __syncthreads();   // all waves done reading Ah -> safe to alias its LDS

  // ---- epilogue: relu(h2+b2)*W3, shfl-reduce, softplus, row sums -----
  float* PL = (float*)Ah;            // [64][PLS], aliases dead A tile
  const float bb0 = b2[wave * 64 + r31];
  const float bb1 = b2[wave * 64 + 32 + r31];
  const float w30 = W3[wave * 64 + r31];
  const float w31 = W3[wave * 64 + 32 + r31];
#pragma unroll
  for (int mt = 0; mt < 2; ++mt) {
#pragma unroll
    for (int r = 0; r < 16; ++r) {
      float v0 = acc[mt][0][r] + bb0;
      float v1 = acc[mt][1][r] + bb1;
      v0 = v0 > 0.f ? v0 : 0.f;            // second relu
      v1 = v1 > 0.f ? v1 : 0.f;
      float p = fmaf(v0, w30, v1 * w31);
      p += __shfl_xor(p, 1);
      p += __shfl_xor(p, 2);
      p += __shfl_xor(p, 4);
      p += __shfl_xor(p, 8);
      p += __shfl_xor(p, 16);
      if (r31 == 0) {
        const int row = mt * 32 + (r & 3) + 8 * (r >> 2) + 4 * half;
        PL[row * PLS + wave] = p;
      }
    }
  }
  __syncthreads();
  if (t < 64) {
    float4 q0 = *(const float4*)(PL + t * PLS);
    float4 q1 = *(const float4*)(PL + t * PLS + 4);
    float s = b3[0] + q0.x + q0.y + q0.z + q0.w + q1.x + q1.y + q1.z + q1.w;
    const float sp = s > 0.f ? s + log1pf(expf(-s)) : log1pf(expf(s));
    const int ti = t >> 3, tj = t & 7;
    const int gi = i0 + ti, gj = j0 + tj;
    if (gi == gj)                           // diag == T0, coherent store
      __hip_atomic_store(t0g + gi, sp, __ATOMIC_RELAXED,
                         __HIP_MEMORY_SCOPE_AGENT);
    float e = expf(sp);
    e += __shfl_xor(e, 1);                 // sum over this tile's 8 j's
    e += __shfl_xor(e, 2);
    e += __shfl_xor(e, 4);
    if (tj == 0) atomicAdd(rsm + gi, e);
  }
  __syncthreads();   // vmcnt(0) drain: data atomics complete before rank

  // ---- last block does the final reduction (NO fences) ---------------
  if (t == 0) rank_s = atomicAdd(ctl, 1);
  __syncthreads();
  if (rank_s == NTILE - 1) {
    float a = __hip_atomic_load(t0g + t, __ATOMIC_RELAXED,
                                __HIP_MEMORY_SCOPE_AGENT);
    float l = logf(__hip_atomic_load(rsm + t, __ATOMIC_RELAXED,
                                     __HIP_MEMORY_SCOPE_AGENT));
#pragma unroll
    for (int off = 1; off < 64; off <<= 1) {
      a += __shfl_xor(a, off);
      l += __shfl_xor(l, off);
    }
    if (lane == 0) { s1[wave] = a; s2[wave] = l; }
    __syncthreads();
    if (t == 0) {
      float sa = 0.f, sb = 0.f;
#pragma unroll
      for (int i = 0; i < 8; ++i) { sa += s1[i]; sb += s2[i]; }
      out[0] = sa / 512.0f - sb / 512.0f + logf(512.0f);
    }
  }
}

// ---------------------------------------------------------------------------
extern "C" void kernel_launch(void* const* d_in, const int* in_sizes, int n_in,
                              void* d_out, int out_size, void* d_ws, size_t ws_size,
                              hipStream_t stream) {
  const float* x   = (const float*)d_in[0];
  const float* y   = (const float*)d_in[1];
  const float* W1x = (const float*)d_in[2];
  const float* W1y = (const float*)d_in[3];
  const float* b1  = (const float*)d_in[4];
  const float* W2  = (const float*)d_in[5];
  const float* b2  = (const float*)d_in[6];
  const float* W3  = (const float*)d_in[7];
  const float* b3  = (const float*)d_in[8];

  float* ws = (float*)d_ws;
  float* hx  = ws;                        // 512*512 f32
  float* hy  = ws + 262144;               // 512*512 f32
  float* t0g = ws + 524288;               // 512 f32 (diag = T0)
  float* rsm = ws + 524288 + 512;         // 512 f32 (row exp-sums)
  int*   ctl = (int*)(ws + 524288 + 1024);// rank counter
  __bf16* w2h = (__bf16*)(ws + 786432);   // 512*512 bf16 (fragment-major)
  __bf16* w2l = w2h + 262144;             // 512*512 bf16
  float* out = (float*)d_out;

  static bool configured = false;
  if (!configured) {
    hipFuncSetAttribute(reinterpret_cast<const void*>(pair_kernel),
                        hipFuncAttributeMaxDynamicSharedMemorySize,
                        64 * SPA * 2);
    configured = true;
  }

  hipLaunchKernelGGL(prep_kernel, dim3(640), dim3(256), 0, stream,
                     x, y, W1x, W1y, b1, W2, hx, hy, w2h, w2l, rsm, ctl);
  hipLaunchKernelGGL(pair_kernel, dim3(NTILE), dim3(512), 64 * SPA * 2, stream,
                     hx, hy, w2h, w2l, b2, W3, b3, t0g, rsm, ctl, out);
}

// Round 12
// 386.664 us; speedup vs baseline: 1.4800x; 1.2102x over previous
//
#include <hip/hip_runtime.h>
#include <math.h>

// ---------------------------------------------------------------------------
// InfoNCE on MI355X — v15.
// T1[i,j] = tail(relu(hx[j]+hy[i]+b1)) = fused GEMM M=262144, N=512, K=512,
// A formed on the fly; 2 MFMA products (A bf16, B hi/lo split), 32x32x16.
// v15 = composition of the three COUNTER-VERIFIED pieces:
//  - v9's spill-free K-loop (unroll 2 + walking pointers; measured WRITE
//    1 MB / FETCH 8.8 MB / 307 us). v13/v14 post-mortem: their 515 MB
//    writes were SPILL (atomic epilogue + rank state added to v8's
//    fully-unrolled loop overflowed the 128-reg cap 4x worse than v8),
//    not fences — v14 removed fences and traffic stayed. v9's loop has
//    ~10 regs of slack for the epilogue additions.
//  - v14's fence-free atomic epilogue + last-block final reduction
//    (ordering via the vmcnt(0) drain in __syncthreads before the rank
//    atomicAdd; relaxed agent-scope atomic loads in the last block;
//    atomics proven free in v10: WRITE 130 KB).
//  - v13's prep (validated twice: 8 rows/block k-outer, W2 repack,
//    rsm/ctl zeroing folded in). 2 dispatches, 1 boundary.
// ---------------------------------------------------------------------------

typedef __bf16 bf16x8 __attribute__((ext_vector_type(8)));
typedef float  f32x16 __attribute__((ext_vector_type(16)));

#define H     512
#define NPTS  512
#define XD    128
#define SPA   520   // A-tile LDS row stride (elems): 1040 B (0 conflicts)
#define PLS   12    // epilogue partial-scratch row stride (f32)
#define NTILE 4096  // 64 i-groups x 64 j-groups (M-tile 64 = 8i x 8j)

// ---------------- prep: hx, hy(+b1); W2 repack; zero rsm/ctl --------------
__global__ __launch_bounds__(256) void prep_kernel(
    const float* __restrict__ x, const float* __restrict__ y,
    const float* __restrict__ W1x, const float* __restrict__ W1y,
    const float* __restrict__ b1, const float* __restrict__ W2,
    float* __restrict__ hx, float* __restrict__ hy,
    __bf16* __restrict__ w2h, __bf16* __restrict__ w2l,
    float* __restrict__ rsm, int* __restrict__ ctl) {
  __shared__ float xs[8 * XD];
  const int b = blockIdx.x;
  const int t = threadIdx.x;
  if (b < 128) {
    const bool isY = (b >= 64);
    const int r0 = (isY ? b - 64 : b) * 8;
    const float* src = isY ? y : x;      // [NPTS][XD]
    const float* W   = isY ? W1y : W1x;  // [XD][H]
    float* dst = isY ? hy : hx;
    for (int i = t; i < 8 * XD; i += 256) xs[i] = src[r0 * XD + i];
    __syncthreads();
    float a0[8], a1[8];
#pragma unroll
    for (int r = 0; r < 8; ++r) { a0[r] = 0.f; a1[r] = 0.f; }
    for (int k = 0; k < XD; ++k) {       // W1 row k read once, used 8x
      const float w0 = W[k * H + t];
      const float w1 = W[k * H + t + 256];
#pragma unroll
      for (int r = 0; r < 8; ++r) {
        const float xv = xs[r * XD + k];   // LDS broadcast
        a0[r] = fmaf(xv, w0, a0[r]);
        a1[r] = fmaf(xv, w1, a1[r]);
      }
    }
    const float c0 = isY ? b1[t] : 0.f;        // fold b1 into hy
    const float c1 = isY ? b1[t + 256] : 0.f;
#pragma unroll
    for (int r = 0; r < 8; ++r) {
      dst[(r0 + r) * H + t]       = a0[r] + c0;
      dst[(r0 + r) * H + t + 256] = a1[r] + c1;
    }
  } else {
    // W2[k][n] -> 32x32x16-fragment-major:
    // idx = ((n>>5)*32 + (k>>4))*512 + (n&31)*16 + (k&15)
    const int n = b - 128;
    if (n == 0) { rsm[t] = 0.f; rsm[t + 256] = 0.f; if (t == 0) ctl[0] = 0; }
    for (int k = t; k < H; k += 256) {
      float v = W2[k * H + n];
      __bf16 hi = (__bf16)v;
      float lo = v - (float)hi;
      const int idx = (((n >> 5) * 32) + (k >> 4)) * 512 + (n & 31) * 16 + (k & 15);
      w2h[idx] = hi;
      w2l[idx] = (__bf16)lo;
    }
  }
}

// ---------------- pair GEMM + fused tail + row sums + final ---------------
// grid 4096; M-tile 64 (8i x 8j); 512 thr / 8 waves; wave tile 64x64
// (acc[2][2] f32x16). K in 32 half-steps of 16; v9 loop: #pragma unroll 2,
// walking pointers (pBh/pBl/pA), A/B reg-double-buffered, barrier-free.
// Epilogue: softplus -> diag coherent-store t0g, row exp-sums atomicAdd.
// NO fences: vmcnt(0) drain in __syncthreads orders data atomics before
// the rank atomicAdd; last block reduces via relaxed agent-scope loads.
__global__ __launch_bounds__(512, 4) void pair_kernel(
    const float* __restrict__ hx, const float* __restrict__ hy,
    const __bf16* __restrict__ w2h, const __bf16* __restrict__ w2l,
    const float* __restrict__ b2, const float* __restrict__ W3,
    const float* __restrict__ b3, float* __restrict__ t0g,
    float* __restrict__ rsm, int* __restrict__ ctl,
    float* __restrict__ out) {
  extern __shared__ __align__(16) __bf16 Ah[];   // [64][SPA] = 66560 B
  __shared__ float s1[8], s2[8];
  __shared__ int rank_s;

  const int t    = threadIdx.x;
  const int i0   = (blockIdx.x >> 6) * 8;
  const int j0   = (blockIdx.x & 63) * 8;
  const int wave = t >> 6;        // n-group 0..7 (cols wave*64..wave*64+63)
  const int lane = t & 63;
  const int r31  = lane & 31;
  const int half = lane >> 5;

  const int boff = r31 * 16 + half * 8;
  const __bf16* w2hW = w2h + wave * 32768 + boff;
  const __bf16* w2lW = w2l + wave * 32768 + boff;

  // issue B loads for half-step 0 before staging (land during it)
  bf16x8 Bh[2][2], Bl[2][2];
  Bh[0][0] = *(const bf16x8*)(w2hW);
  Bh[0][1] = *(const bf16x8*)(w2hW + 16384);
  Bl[0][0] = *(const bf16x8*)(w2lW);
  Bl[0][1] = *(const bf16x8*)(w2lW + 16384);

  // ---- upfront staging of the whole 64 x 512 A tile ------------------
  {
    const int sm = t >> 3;        // pair row 0..63  (ti = sm>>3, tj = sm&7)
    const int sl = t & 7;
    const float* hxp = hx + (j0 + (sm & 7)) * H;
    const float* hyp = hy + (i0 + (sm >> 3)) * H;
    __bf16* arow = Ah + sm * SPA;
#pragma unroll
    for (int c = 0; c < 8; ++c) {
      const int k = sl * 8 + c * 64;
      float4 x0 = *(const float4*)(hxp + k);
      float4 x1 = *(const float4*)(hxp + k + 4);
      float4 y0 = *(const float4*)(hyp + k);
      float4 y1 = *(const float4*)(hyp + k + 4);
      float a[8] = {x0.x + y0.x, x0.y + y0.y, x0.z + y0.z, x0.w + y0.w,
                    x1.x + y1.x, x1.y + y1.y, x1.z + y1.z, x1.w + y1.w};
      bf16x8 hv;
#pragma unroll
      for (int e = 0; e < 8; ++e) {
        float v = a[e] > 0.f ? a[e] : 0.f;   // first relu
        hv[e] = (__bf16)v;
      }
      *(bf16x8*)(&arow[k]) = hv;
    }
  }

  f32x16 acc[2][2] = {};
  __syncthreads();   // staging complete; only barrier before epilogue

  // walking pointers (the ONLY per-iter address state: +512 / +16 elems)
  const __bf16* pBh = w2hW;
  const __bf16* pBl = w2lW;
  const __bf16* pA  = Ah + r31 * SPA + half * 8;

  bf16x8 Ab[2][2];
  Ab[0][0] = *(const bf16x8*)(pA);
  Ab[0][1] = *(const bf16x8*)(pA + 32 * SPA);

  // ---- barrier-free K-loop: 32 half-steps of K=16 (v9 loop) ----------
#pragma unroll 2
  for (int hs = 0; hs < 32; ++hs) {
    const int cur = hs & 1;
    if (hs < 31) {   // prefetch B and A for next half-step
      Bh[cur ^ 1][0] = *(const bf16x8*)(pBh + 512);
      Bh[cur ^ 1][1] = *(const bf16x8*)(pBh + 16384 + 512);
      Bl[cur ^ 1][0] = *(const bf16x8*)(pBl + 512);
      Bl[cur ^ 1][1] = *(const bf16x8*)(pBl + 16384 + 512);
      Ab[cur ^ 1][0] = *(const bf16x8*)(pA + 16);
      Ab[cur ^ 1][1] = *(const bf16x8*)(pA + 32 * SPA + 16);
      pBh += 512; pBl += 512; pA += 16;
    }
    __builtin_amdgcn_s_setprio(1);
    acc[0][0] = __builtin_amdgcn_mfma_f32_32x32x16_bf16(Ab[cur][0], Bh[cur][0], acc[0][0], 0, 0, 0);
    acc[0][1] = __builtin_amdgcn_mfma_f32_32x32x16_bf16(Ab[cur][0], Bh[cur][1], acc[0][1], 0, 0, 0);
    acc[1][0] = __builtin_amdgcn_mfma_f32_32x32x16_bf16(Ab[cur][1], Bh[cur][0], acc[1][0], 0, 0, 0);
    acc[1][1] = __builtin_amdgcn_mfma_f32_32x32x16_bf16(Ab[cur][1], Bh[cur][1], acc[1][1], 0, 0, 0);
    acc[0][0] = __builtin_amdgcn_mfma_f32_32x32x16_bf16(Ab[cur][0], Bl[cur][0], acc[0][0], 0, 0, 0);
    acc[0][1] = __builtin_amdgcn_mfma_f32_32x32x16_bf16(Ab[cur][0], Bl[cur][1], acc[0][1], 0, 0, 0);
    acc[1][0] = __builtin_amdgcn_mfma_f32_32x32x16_bf16(Ab[cur][1], Bl[cur][0], acc[1][0], 0, 0, 0);
    acc[1][1] = __builtin_amdgcn_mfma_f32_32x32x16_bf16(Ab[cur][1], Bl[cur][1], acc[1][1], 0, 0, 0);
    __builtin_amdgcn_s_setprio(0);
  }

  __syncthreads();   // all waves done reading Ah -> safe to alias its LDS

  // ---- epilogue: relu(h2+b2)*W3, shfl-reduce, softplus, row sums -----
  float* PL = (float*)Ah;            // [64][PLS], aliases dead A tile
  const float bb0 = b2[wave * 64 + r31];
  const float bb1 = b2[wave * 64 + 32 + r31];
  const float w30 = W3[wave * 64 + r31];
  const float w31 = W3[wave * 64 + 32 + r31];
#pragma unroll
  for (int mt = 0; mt < 2; ++mt) {
#pragma unroll
    for (int r = 0; r < 16; ++r) {
      float v0 = acc[mt][0][r] + bb0;
      float v1 = acc[mt][1][r] + bb1;
      v0 = v0 > 0.f ? v0 : 0.f;            // second relu
      v1 = v1 > 0.f ? v1 : 0.f;
      float p = fmaf(v0, w30, v1 * w31);
      p += __shfl_xor(p, 1);
      p += __shfl_xor(p, 2);
      p += __shfl_xor(p, 4);
      p += __shfl_xor(p, 8);
      p += __shfl_xor(p, 16);
      if (r31 == 0) {
        const int row = mt * 32 + (r & 3) + 8 * (r >> 2) + 4 * half;
        PL[row * PLS + wave] = p;
      }
    }
  }
  __syncthreads();
  if (t < 64) {
    float4 q0 = *(const float4*)(PL + t * PLS);
    float4 q1 = *(const float4*)(PL + t * PLS + 4);
    float s = b3[0] + q0.x + q0.y + q0.z + q0.w + q1.x + q1.y + q1.z + q1.w;
    const float sp = s > 0.f ? s + log1pf(expf(-s)) : log1pf(expf(s));
    const int ti = t >> 3, tj = t & 7;
    const int gi = i0 + ti, gj = j0 + tj;
    if (gi == gj)                           // diag == T0, coherent store
      __hip_atomic_store(t0g + gi, sp, __ATOMIC_RELAXED,
                         __HIP_MEMORY_SCOPE_AGENT);
    float e = expf(sp);
    e += __shfl_xor(e, 1);                 // sum over this tile's 8 j's
    e += __shfl_xor(e, 2);
    e += __shfl_xor(e, 4);
    if (tj == 0) atomicAdd(rsm + gi, e);
  }
  __syncthreads();   // vmcnt(0) drain: data atomics complete before rank

  // ---- last block does the final reduction (NO fences) ---------------
  if (t == 0) rank_s = atomicAdd(ctl, 1);
  __syncthreads();
  if (rank_s == NTILE - 1) {
    float a = __hip_atomic_load(t0g + t, __ATOMIC_RELAXED,
                                __HIP_MEMORY_SCOPE_AGENT);
    float l = logf(__hip_atomic_load(rsm + t, __ATOMIC_RELAXED,
                                     __HIP_MEMORY_SCOPE_AGENT));
#pragma unroll
    for (int off = 1; off < 64; off <<= 1) {
      a += __shfl_xor(a, off);
      l += __shfl_xor(l, off);
    }
    if (lane == 0) { s1[wave] = a; s2[wave] = l; }
    __syncthreads();
    if (t == 0) {
      float sa = 0.f, sb = 0.f;
#pragma unroll
      for (int i = 0; i < 8; ++i) { sa += s1[i]; sb += s2[i]; }
      out[0] = sa / 512.0f - sb / 512.0f + logf(512.0f);
    }
  }
}

// ---------------------------------------------------------------------------
extern "C" void kernel_launch(void* const* d_in, const int* in_sizes, int n_in,
                              void* d_out, int out_size, void* d_ws, size_t ws_size,
                              hipStream_t stream) {
  const float* x   = (const float*)d_in[0];
  const float* y   = (const float*)d_in[1];
  const float* W1x = (const float*)d_in[2];
  const float* W1y = (const float*)d_in[3];
  const float* b1  = (const float*)d_in[4];
  const float* W2  = (const float*)d_in[5];
  const float* b2  = (const float*)d_in[6];
  const float* W3  = (const float*)d_in[7];
  const float* b3  = (const float*)d_in[8];

  float* ws = (float*)d_ws;
  float* hx  = ws;                        // 512*512 f32
  float* hy  = ws + 262144;               // 512*512 f32
  float* t0g = ws + 524288;               // 512 f32 (diag = T0)
  float* rsm = ws + 524288 + 512;         // 512 f32 (row exp-sums)
  int*   ctl = (int*)(ws + 524288 + 1024);// rank counter
  __bf16* w2h = (__bf16*)(ws + 786432);   // 512*512 bf16 (fragment-major)
  __bf16* w2l = w2h + 262144;             // 512*512 bf16
  float* out = (float*)d_out;

  static bool configured = false;
  if (!configured) {
    hipFuncSetAttribute(reinterpret_cast<const void*>(pair_kernel),
                        hipFuncAttributeMaxDynamicSharedMemorySize,
                        64 * SPA * 2);
    configured = true;
  }

  hipLaunchKernelGGL(prep_kernel, dim3(640), dim3(256), 0, stream,
                     x, y, W1x, W1y, b1, W2, hx, hy, w2h, w2l, rsm, ctl);
  hipLaunchKernelGGL(pair_kernel, dim3(NTILE), dim3(512), 64 * SPA * 2, stream,
                     hx, hy, w2h, w2l, b2, W3, b3, t0g, rsm, ctl, out);
}

// Round 13
// 259.757 us; speedup vs baseline: 2.2031x; 1.4886x over previous
//
#include <hip/hip_runtime.h>
#include <math.h>

// ---------------------------------------------------------------------------
// InfoNCE on MI355X — v16.
// T1[i,j] = tail(relu(hx[j]+hy[i]+b1)) = fused GEMM M=262144, N=512, K=512,
// A formed on the fly; ONE MFMA product (A bf16 x W2 bf16), 32x32x16.
// v16 vs v15: drop the Bl (W2 lo-residual) product. Error analysis: the
// W2-rounding error induces a per-column bias in h2 whose T1 effect is
// ~uniform over (i,j); out = mean(T0) - mean(lse) cancels uniform shifts
// EXACTLY, leaving only the A-fluctuation-coupled part (~2-5e-6 on the
// scalar). Est. total absmax ~1.0-1.5e-5 < 2.3e-5 threshold. Payoff:
// MFMA work halves (floor 132->66 us), B L2 traffic halves (2 GB), and
// the freed 32 regs fund a 2-DEEP B prefetch (Bh[4][2], unroll 4, walking
// pointers - v9's anti-spill discipline) against the exposed-latency term
// that pinned five structures at 37-43% util. prep skips w2l entirely.
// Everything else = v15 verbatim (counter-verified: WRITE 258 KB, FETCH
// 8.8 MB, fence-free atomic epilogue + last-block final reduction).
// ---------------------------------------------------------------------------

typedef __bf16 bf16x8 __attribute__((ext_vector_type(8)));
typedef float  f32x16 __attribute__((ext_vector_type(16)));

#define H     512
#define NPTS  512
#define XD    128
#define SPA   520   // A-tile LDS row stride (elems): 1040 B (0 conflicts)
#define PLS   12    // epilogue partial-scratch row stride (f32)
#define NTILE 4096  // 64 i-groups x 64 j-groups (M-tile 64 = 8i x 8j)

// ---------------- prep: hx, hy(+b1); W2 -> bf16 fragment-major; zero ------
__global__ __launch_bounds__(256) void prep_kernel(
    const float* __restrict__ x, const float* __restrict__ y,
    const float* __restrict__ W1x, const float* __restrict__ W1y,
    const float* __restrict__ b1, const float* __restrict__ W2,
    float* __restrict__ hx, float* __restrict__ hy,
    __bf16* __restrict__ w2h,
    float* __restrict__ rsm, int* __restrict__ ctl) {
  __shared__ float xs[8 * XD];
  const int b = blockIdx.x;
  const int t = threadIdx.x;
  if (b < 128) {
    const bool isY = (b >= 64);
    const int r0 = (isY ? b - 64 : b) * 8;
    const float* src = isY ? y : x;      // [NPTS][XD]
    const float* W   = isY ? W1y : W1x;  // [XD][H]
    float* dst = isY ? hy : hx;
    for (int i = t; i < 8 * XD; i += 256) xs[i] = src[r0 * XD + i];
    __syncthreads();
    float a0[8], a1[8];
#pragma unroll
    for (int r = 0; r < 8; ++r) { a0[r] = 0.f; a1[r] = 0.f; }
    for (int k = 0; k < XD; ++k) {       // W1 row k read once, used 8x
      const float w0 = W[k * H + t];
      const float w1 = W[k * H + t + 256];
#pragma unroll
      for (int r = 0; r < 8; ++r) {
        const float xv = xs[r * XD + k];   // LDS broadcast
        a0[r] = fmaf(xv, w0, a0[r]);
        a1[r] = fmaf(xv, w1, a1[r]);
      }
    }
    const float c0 = isY ? b1[t] : 0.f;        // fold b1 into hy
    const float c1 = isY ? b1[t + 256] : 0.f;
#pragma unroll
    for (int r = 0; r < 8; ++r) {
      dst[(r0 + r) * H + t]       = a0[r] + c0;
      dst[(r0 + r) * H + t + 256] = a1[r] + c1;
    }
  } else {
    // W2[k][n] -> 32x32x16-fragment-major bf16 (hi only):
    // idx = ((n>>5)*32 + (k>>4))*512 + (n&31)*16 + (k&15)
    const int n = b - 128;
    if (n == 0) { rsm[t] = 0.f; rsm[t + 256] = 0.f; if (t == 0) ctl[0] = 0; }
    for (int k = t; k < H; k += 256) {
      const int idx = (((n >> 5) * 32) + (k >> 4)) * 512 + (n & 31) * 16 + (k & 15);
      w2h[idx] = (__bf16)W2[k * H + n];
    }
  }
}

// ---------------- pair GEMM + fused tail + row sums + final ---------------
// grid 4096; M-tile 64 (8i x 8j); 512 thr / 8 waves; wave tile 64x64
// (acc[2][2] f32x16). K in 32 half-steps of 16; ONE product per (mt,nt);
// B 2-deep prefetched in Bh[4][2] (unroll 4, walking pointers), A 1-deep
// from LDS. Barrier-free. Fence-free atomic epilogue + last-block final.
__global__ __launch_bounds__(512, 4) void pair_kernel(
    const float* __restrict__ hx, const float* __restrict__ hy,
    const __bf16* __restrict__ w2h,
    const float* __restrict__ b2, const float* __restrict__ W3,
    const float* __restrict__ b3, float* __restrict__ t0g,
    float* __restrict__ rsm, int* __restrict__ ctl,
    float* __restrict__ out) {
  extern __shared__ __align__(16) __bf16 Ah[];   // [64][SPA] = 66560 B
  __shared__ float s1[8], s2[8];
  __shared__ int rank_s;

  const int t    = threadIdx.x;
  const int i0   = (blockIdx.x >> 6) * 8;
  const int j0   = (blockIdx.x & 63) * 8;
  const int wave = t >> 6;        // n-group 0..7 (cols wave*64..wave*64+63)
  const int lane = t & 63;
  const int r31  = lane & 31;
  const int half = lane >> 5;

  const int boff = r31 * 16 + half * 8;
  const __bf16* w2hW = w2h + wave * 32768 + boff;

  // issue B loads for half-steps 0 AND 1 before staging (land during it)
  bf16x8 Bh[4][2];
  Bh[0][0] = *(const bf16x8*)(w2hW);
  Bh[0][1] = *(const bf16x8*)(w2hW + 16384);
  Bh[1][0] = *(const bf16x8*)(w2hW + 512);
  Bh[1][1] = *(const bf16x8*)(w2hW + 16384 + 512);

  // ---- upfront staging of the whole 64 x 512 A tile ------------------
  {
    const int sm = t >> 3;        // pair row 0..63  (ti = sm>>3, tj = sm&7)
    const int sl = t & 7;
    const float* hxp = hx + (j0 + (sm & 7)) * H;
    const float* hyp = hy + (i0 + (sm >> 3)) * H;
    __bf16* arow = Ah + sm * SPA;
#pragma unroll
    for (int c = 0; c < 8; ++c) {
      const int k = sl * 8 + c * 64;
      float4 x0 = *(const float4*)(hxp + k);
      float4 x1 = *(const float4*)(hxp + k + 4);
      float4 y0 = *(const float4*)(hyp + k);
      float4 y1 = *(const float4*)(hyp + k + 4);
      float a[8] = {x0.x + y0.x, x0.y + y0.y, x0.z + y0.z, x0.w + y0.w,
                    x1.x + y1.x, x1.y + y1.y, x1.z + y1.z, x1.w + y1.w};
      bf16x8 hv;
#pragma unroll
      for (int e = 0; e < 8; ++e) {
        float v = a[e] > 0.f ? a[e] : 0.f;   // first relu
        hv[e] = (__bf16)v;
      }
      *(bf16x8*)(&arow[k]) = hv;
    }
  }

  f32x16 acc[2][2] = {};
  __syncthreads();   // staging complete; only barrier before epilogue

  // walking pointers (the ONLY per-iter address state: +512 / +16 elems)
  const __bf16* pBh = w2hW;
  const __bf16* pA  = Ah + r31 * SPA + half * 8;

  bf16x8 Ab[2][2];
  Ab[0][0] = *(const bf16x8*)(pA);
  Ab[0][1] = *(const bf16x8*)(pA + 32 * SPA);

  // ---- barrier-free K-loop: 32 half-steps, B prefetched 2 deep -------
#pragma unroll 4
  for (int hs = 0; hs < 32; ++hs) {
    const int cur = hs & 3;
    const int ca  = hs & 1;
    if (hs < 30) {   // prefetch B for half-step hs+2 (2-deep)
      Bh[(hs + 2) & 3][0] = *(const bf16x8*)(pBh + 1024);
      Bh[(hs + 2) & 3][1] = *(const bf16x8*)(pBh + 16384 + 1024);
    }
    if (hs < 31) {   // prefetch A for half-step hs+1 (LDS, short latency)
      Ab[ca ^ 1][0] = *(const bf16x8*)(pA + 16);
      Ab[ca ^ 1][1] = *(const bf16x8*)(pA + 32 * SPA + 16);
    }
    pBh += 512; pA += 16;
    __builtin_amdgcn_s_setprio(1);
    acc[0][0] = __builtin_amdgcn_mfma_f32_32x32x16_bf16(Ab[ca][0], Bh[cur][0], acc[0][0], 0, 0, 0);
    acc[0][1] = __builtin_amdgcn_mfma_f32_32x32x16_bf16(Ab[ca][0], Bh[cur][1], acc[0][1], 0, 0, 0);
    acc[1][0] = __builtin_amdgcn_mfma_f32_32x32x16_bf16(Ab[ca][1], Bh[cur][0], acc[1][0], 0, 0, 0);
    acc[1][1] = __builtin_amdgcn_mfma_f32_32x32x16_bf16(Ab[ca][1], Bh[cur][1], acc[1][1], 0, 0, 0);
    __builtin_amdgcn_s_setprio(0);
  }

  __syncthreads();   // all waves done reading Ah -> safe to alias its LDS

  // ---- epilogue: relu(h2+b2)*W3, shfl-reduce, softplus, row sums -----
  float* PL = (float*)Ah;            // [64][PLS], aliases dead A tile
  const float bb0 = b2[wave * 64 + r31];
  const float bb1 = b2[wave * 64 + 32 + r31];
  const float w30 = W3[wave * 64 + r31];
  const float w31 = W3[wave * 64 + 32 + r31];
#pragma unroll
  for (int mt = 0; mt < 2; ++mt) {
#pragma unroll
    for (int r = 0; r < 16; ++r) {
      float v0 = acc[mt][0][r] + bb0;
      float v1 = acc[mt][1][r] + bb1;
      v0 = v0 > 0.f ? v0 : 0.f;            // second relu
      v1 = v1 > 0.f ? v1 : 0.f;
      float p = fmaf(v0, w30, v1 * w31);
      p += __shfl_xor(p, 1);
      p += __shfl_xor(p, 2);
      p += __shfl_xor(p, 4);
      p += __shfl_xor(p, 8);
      p += __shfl_xor(p, 16);
      if (r31 == 0) {
        const int row = mt * 32 + (r & 3) + 8 * (r >> 2) + 4 * half;
        PL[row * PLS + wave] = p;
      }
    }
  }
  __syncthreads();
  if (t < 64) {
    float4 q0 = *(const float4*)(PL + t * PLS);
    float4 q1 = *(const float4*)(PL + t * PLS + 4);
    float s = b3[0] + q0.x + q0.y + q0.z + q0.w + q1.x + q1.y + q1.z + q1.w;
    const float sp = s > 0.f ? s + log1pf(expf(-s)) : log1pf(expf(s));
    const int ti = t >> 3, tj = t & 7;
    const int gi = i0 + ti, gj = j0 + tj;
    if (gi == gj)                           // diag == T0, coherent store
      __hip_atomic_store(t0g + gi, sp, __ATOMIC_RELAXED,
                         __HIP_MEMORY_SCOPE_AGENT);
    float e = expf(sp);
    e += __shfl_xor(e, 1);                 // sum over this tile's 8 j's
    e += __shfl_xor(e, 2);
    e += __shfl_xor(e, 4);
    if (tj == 0) atomicAdd(rsm + gi, e);
  }
  __syncthreads();   // vmcnt(0) drain: data atomics complete before rank

  // ---- last block does the final reduction (NO fences) ---------------
  if (t == 0) rank_s = atomicAdd(ctl, 1);
  __syncthreads();
  if (rank_s == NTILE - 1) {
    float a = __hip_atomic_load(t0g + t, __ATOMIC_RELAXED,
                                __HIP_MEMORY_SCOPE_AGENT);
    float l = logf(__hip_atomic_load(rsm + t, __ATOMIC_RELAXED,
                                     __HIP_MEMORY_SCOPE_AGENT));
#pragma unroll
    for (int off = 1; off < 64; off <<= 1) {
      a += __shfl_xor(a, off);
      l += __shfl_xor(l, off);
    }
    if (lane == 0) { s1[wave] = a; s2[wave] = l; }
    __syncthreads();
    if (t == 0) {
      float sa = 0.f, sb = 0.f;
#pragma unroll
      for (int i = 0; i < 8; ++i) { sa += s1[i]; sb += s2[i]; }
      out[0] = sa / 512.0f - sb / 512.0f + logf(512.0f);
    }
  }
}

// ---------------------------------------------------------------------------
extern "C" void kernel_launch(void* const* d_in, const int* in_sizes, int n_in,
                              void* d_out, int out_size, void* d_ws, size_t ws_size,
                              hipStream_t stream) {
  const float* x   = (const float*)d_in[0];
  const float* y   = (const float*)d_in[1];
  const float* W1x = (const float*)d_in[2];
  const float* W1y = (const float*)d_in[3];
  const float* b1  = (const float*)d_in[4];
  const float* W2  = (const float*)d_in[5];
  const float* b2  = (const float*)d_in[6];
  const float* W3  = (const float*)d_in[7];
  const float* b3  = (const float*)d_in[8];

  float* ws = (float*)d_ws;
  float* hx  = ws;                        // 512*512 f32
  float* hy  = ws + 262144;               // 512*512 f32
  float* t0g = ws + 524288;               // 512 f32 (diag = T0)
  float* rsm = ws + 524288 + 512;         // 512 f32 (row exp-sums)
  int*   ctl = (int*)(ws + 524288 + 1024);// rank counter
  __bf16* w2h = (__bf16*)(ws + 786432);   // 512*512 bf16 (fragment-major)
  float* out = (float*)d_out;

  static bool configured = false;
  if (!configured) {
    hipFuncSetAttribute(reinterpret_cast<const void*>(pair_kernel),
                        hipFuncAttributeMaxDynamicSharedMemorySize,
                        64 * SPA * 2);
    configured = true;
  }

  hipLaunchKernelGGL(prep_kernel, dim3(640), dim3(256), 0, stream,
                     x, y, W1x, W1y, b1, W2, hx, hy, w2h, rsm, ctl);
  hipLaunchKernelGGL(pair_kernel, dim3(NTILE), dim3(512), 64 * SPA * 2, stream,
                     hx, hy, w2h, b2, W3, b3, t0g, rsm, ctl, out);
}